// Round 2
// baseline (321.586 us; speedup 1.0000x reference)
//
#include <hip/hip_runtime.h>
#include <hip/hip_bf16.h>
#include <stdint.h>

// Problem constants (from reference setup_inputs)
#define B_   8
#define ND   1024
#define VOC  30001
#define D_   100
#define NV   30000
#define NC   512
#define KP   128      // K padded to 128 for 4x mfma_16x16x32
#define NVP  30016    // Nv padded to 469*64
#define NVT  469      // number of 64-wide v tiles

typedef float f32x4 __attribute__((ext_vector_type(4)));
typedef short s16x8 __attribute__((ext_vector_type(8)));

static __device__ __forceinline__ unsigned short f2bf(float x) {
    union { float f; uint32_t u; } v; v.f = x;
    uint32_t u = v.u;
    return (unsigned short)((u + 0x7FFFu + ((u >> 16) & 1u)) >> 16);  // RNE
}

// --- prep: bin_w[k] = start + cumsum(relu(diff))[k] ---
__global__ void k_binw(const float* __restrict__ diff, const float* __restrict__ start,
                       float* __restrict__ binw) {
    if (threadIdx.x == 0) {
        float s = start[0];
        for (int i = 0; i < 16; ++i) {
            float d = diff[i]; if (d < 0.f) d = 0.f;
            s += d; binw[i] = s;
        }
    }
}

__global__ void k_zero(float* __restrict__ p, int n) {
    int i = blockIdx.x * blockDim.x + threadIdx.x;
    if (i < n) p[i] = 0.f;
}

// --- prep: G[m][k] = bf16(emb[doc[m]][k]), k padded to 128 with zeros ---
__global__ void k_gather(const int* __restrict__ doc, const float* __restrict__ emb,
                         unsigned short* __restrict__ G) {
    int m = blockIdx.x;          // 0..8191
    int t = threadIdx.x;         // 0..127
    int idx = doc[m];
    float v = (t < D_) ? emb[idx * D_ + t] : 0.f;
    G[m * KP + t] = f2bf(v);
}

// --- prep: Vbf[v][k] = bf16(Vv_T[k][v]); rows >= NV and k >= D_ zeroed ---
__global__ void k_vt(const float* __restrict__ VvT, unsigned short* __restrict__ Vbf) {
    __shared__ unsigned short tile[64][136];   // +8 pad to break write conflicts
    int v0 = blockIdx.x * 64;
    int tv = threadIdx.x & 63;
    int tk0 = threadIdx.x >> 6;                // 0..3
    for (int k = tk0; k < KP; k += 4) {
        float val = 0.f;
        int v = v0 + tv;
        if (k < D_ && v < NV) val = VvT[k * NV + v];
        tile[tv][k] = f2bf(val);
    }
    __syncthreads();
    for (int c = threadIdx.x; c < 1024; c += 256) {   // 64 rows x 16 chunks of 16B
        int row = c >> 4, ch = c & 15;
        *reinterpret_cast<s16x8*>(&Vbf[(v0 + row) * KP + ch * 8]) =
            *reinterpret_cast<const s16x8*>(&tile[row][ch * 8]);
    }
}

// --- main: sim = G_b @ Vbf^T tile, fused digitize + bin_w lookup + attn-weighted d-reduce ---
__global__ __launch_bounds__(256) void k_main(const unsigned short* __restrict__ G,
                                              const unsigned short* __restrict__ Vbf,
                                              const float* __restrict__ attn,
                                              const float* __restrict__ binw,
                                              float* __restrict__ weighted) {
    const int b   = blockIdx.x / NVT;
    const int vt  = blockIdx.x % NVT;
    const int v0  = vt * 64;
    const int lane = threadIdx.x & 63;
    const int wv   = threadIdx.x >> 6;   // 0..3, owns d range [wv*256, wv*256+256)
    const int lr   = lane & 15;
    const int grp  = lane >> 4;          // 0..3

    // B fragments: 4 col-tiles x 4 k-chunks, resident in VGPRs for whole kernel
    s16x8 bf[4][4];
#pragma unroll
    for (int ct = 0; ct < 4; ++ct)
#pragma unroll
        for (int kc = 0; kc < 4; ++kc)
            bf[ct][kc] = *reinterpret_cast<const s16x8*>(
                &Vbf[(size_t)(v0 + ct * 16 + lr) * KP + grp * 8 + kc * 32]);

    const float wl = binw[lr];           // lane holds bin_w[lane&15]
    const int shbase = lane & 48;

    const float invD = 14.0f / 1.49f;            // 1/bin spacing
    const float C0   = 0.5f * invD + 1.0f;       // digit = floor(sim*invD + C0)

    float acc[4] = {0.f, 0.f, 0.f, 0.f};
    const float* attb = attn + b * ND;
    const unsigned short* Gb = G + (size_t)(b * ND) * KP;

    const int dend = wv * 256 + 256;
    for (int d0 = wv * 256; d0 < dend; d0 += 16) {
        s16x8 af[4];
#pragma unroll
        for (int kc = 0; kc < 4; ++kc)
            af[kc] = *reinterpret_cast<const s16x8*>(
                &Gb[(size_t)(d0 + lr) * KP + grp * 8 + kc * 32]);
        float4 a4 = *reinterpret_cast<const float4*>(&attb[d0 + grp * 4]);
        float at[4] = {a4.x, a4.y, a4.z, a4.w};
#pragma unroll
        for (int ct = 0; ct < 4; ++ct) {
            f32x4 c = {0.f, 0.f, 0.f, 0.f};
#pragma unroll
            for (int kc = 0; kc < 4; ++kc)
                c = __builtin_amdgcn_mfma_f32_16x16x32_bf16(af[kc], bf[ct][kc], c, 0, 0, 0);
            // C layout: col = lane&15, row = (lane>>4)*4 + r
#pragma unroll
            for (int r = 0; r < 4; ++r) {
                float x = fmaf(c[r], invD, C0);
                int di = (int)floorf(x);
                di = di < 0 ? 0 : (di > 15 ? 15 : di);
                float w = __shfl(wl, shbase | di, 64);
                acc[ct] = fmaf(at[r], w, acc[ct]);
            }
        }
    }

    // reduce across the 4 row-groups (lanes sharing lane&15), then one atomic per col
#pragma unroll
    for (int ct = 0; ct < 4; ++ct) {
        float a = acc[ct];
        a += __shfl_xor(a, 16, 64);
        a += __shfl_xor(a, 32, 64);
        if (lane < 16)
            atomicAdd(&weighted[b * NVP + v0 + ct * 16 + lane], a);
    }
}

// --- final: out[b,n] = (sum_v weighted[b,v]*phi_vs[n,v]) / max(L1(phi_vs[n,:]),1e-12) ---
__global__ void k_final(const float* __restrict__ phi, const float* __restrict__ weighted,
                        float* __restrict__ out) {
    const int n0 = blockIdx.x * 4;
    const int t = threadIdx.x;   // 512 threads = 8 waves
    float s1[4] = {0.f, 0.f, 0.f, 0.f};
    float dot[4][8];
#pragma unroll
    for (int nn = 0; nn < 4; ++nn)
#pragma unroll
        for (int b = 0; b < 8; ++b) dot[nn][b] = 0.f;

    for (int v4 = t; v4 < NV / 4; v4 += 512) {
        float4 w4[8];
#pragma unroll
        for (int b = 0; b < 8; ++b)
            w4[b] = *reinterpret_cast<const float4*>(&weighted[b * NVP + v4 * 4]);
#pragma unroll
        for (int nn = 0; nn < 4; ++nn) {
            float4 p = *reinterpret_cast<const float4*>(&phi[(size_t)(n0 + nn) * NV + v4 * 4]);
            s1[nn] += fabsf(p.x) + fabsf(p.y) + fabsf(p.z) + fabsf(p.w);
#pragma unroll
            for (int b = 0; b < 8; ++b)
                dot[nn][b] += p.x * w4[b].x + p.y * w4[b].y + p.z * w4[b].z + p.w * w4[b].w;
        }
    }

    float vals[36];
#pragma unroll
    for (int nn = 0; nn < 4; ++nn) vals[nn] = s1[nn];
#pragma unroll
    for (int nn = 0; nn < 4; ++nn)
#pragma unroll
        for (int b = 0; b < 8; ++b) vals[4 + nn * 8 + b] = dot[nn][b];

    __shared__ float red[8][36];
    __shared__ float sums[36];
    const int lane = t & 63, wvv = t >> 6;
#pragma unroll
    for (int i = 0; i < 36; ++i) {
        float x = vals[i];
        x += __shfl_down(x, 32, 64);
        x += __shfl_down(x, 16, 64);
        x += __shfl_down(x, 8, 64);
        x += __shfl_down(x, 4, 64);
        x += __shfl_down(x, 2, 64);
        x += __shfl_down(x, 1, 64);
        if (lane == 0) red[wvv][i] = x;
    }
    __syncthreads();
    if (t < 36) {
        float s = 0.f;
        for (int w = 0; w < 8; ++w) s += red[w][t];
        sums[t] = s;
    }
    __syncthreads();
    if (t < 32) {
        int nn = t >> 3, b = t & 7;
        float denom = sums[nn]; if (denom < 1e-12f) denom = 1e-12f;
        out[b * NC + n0 + nn] = sums[4 + t] / denom;
    }
}

extern "C" void kernel_launch(void* const* d_in, const int* in_sizes, int n_in,
                              void* d_out, int out_size, void* d_ws, size_t ws_size,
                              hipStream_t stream) {
    const int*   doc   = (const int*)d_in[0];
    const float* attn  = (const float*)d_in[1];
    const float* emb   = (const float*)d_in[2];
    const float* VvT   = (const float*)d_in[3];
    const float* phi   = (const float*)d_in[4];
    const float* diff  = (const float*)d_in[5];
    const float* start = (const float*)d_in[6];

    char* ws = (char*)d_ws;
    unsigned short* Vbf = (unsigned short*)ws;                       // 30016*128*2 = 7,684,096 B
    unsigned short* G   = (unsigned short*)(ws + 7684096);           // 8192*128*2  = 2,097,152 B
    float* weighted     = (float*)(ws + 7684096 + 2097152);          // 8*30016*4   =   960,512 B
    float* binw         = (float*)(ws + 7684096 + 2097152 + 960512); // 64 B
    float* out          = (float*)d_out;

    k_binw  <<<1, 64, 0, stream>>>(diff, start, binw);
    k_gather<<<B_ * ND, 128, 0, stream>>>(doc, emb, G);
    k_vt    <<<NVT, 256, 0, stream>>>(VvT, Vbf);
    k_zero  <<<(B_ * NVP + 255) / 256, 256, 0, stream>>>(weighted, B_ * NVP);
    k_main  <<<B_ * NVT, 256, 0, stream>>>(G, Vbf, attn, binw, weighted);
    k_final <<<NC / 4, 512, 0, stream>>>(phi, weighted, out);
}

// Round 3
// 302.687 us; speedup vs baseline: 1.0624x; 1.0624x over previous
//
#include <hip/hip_runtime.h>
#include <hip/hip_bf16.h>
#include <stdint.h>

#define B_   8
#define ND   1024
#define VOC  30001
#define D_   100
#define NV   30000
#define NC   512
#define KP   128      // K padded to 128 for 4x mfma_16x16x32
#define NVP  30016    // Nv padded to 469*64
#define NVT  469      // number of 64-wide v tiles

typedef float f32x4 __attribute__((ext_vector_type(4)));
typedef short s16x8 __attribute__((ext_vector_type(8)));

static __device__ __forceinline__ unsigned short f2bf(float x) {
    union { float f; uint32_t u; } v; v.f = x;
    uint32_t u = v.u;
    return (unsigned short)((u + 0x7FFFu + ((u >> 16) & 1u)) >> 16);  // RNE
}

// --- fused prep: blocks [0,4096) gather G; blocks [4096,4565) transpose Vv_T ---
__global__ __launch_bounds__(256) void k_prep(const int* __restrict__ doc,
                                              const float* __restrict__ emb,
                                              const float* __restrict__ VvT,
                                              unsigned short* __restrict__ G,
                                              unsigned short* __restrict__ Vbf) {
    if (blockIdx.x < 4096) {
        int m = blockIdx.x * 2 + (threadIdx.x >> 7);   // 2 rows per block
        int t = threadIdx.x & 127;
        int idx = doc[m];
        float v = (t < D_) ? emb[idx * D_ + t] : 0.f;
        G[m * KP + t] = f2bf(v);
    } else {
        __shared__ unsigned short tile[64][136];
        int v0 = (blockIdx.x - 4096) * 64;
        int tv = threadIdx.x & 63;
        int tk0 = threadIdx.x >> 6;
        for (int k = tk0; k < KP; k += 4) {
            float val = 0.f;
            int v = v0 + tv;
            if (k < D_ && v < NV) val = VvT[k * NV + v];
            tile[tv][k] = f2bf(val);
        }
        __syncthreads();
        for (int c = threadIdx.x; c < 1024; c += 256) {
            int row = c >> 4, ch = c & 15;
            *reinterpret_cast<s16x8*>(&Vbf[(v0 + row) * KP + ch * 8]) =
                *reinterpret_cast<const s16x8*>(&tile[row][ch * 8]);
        }
    }
}

// --- main: sim tile via MFMA, batched digitize+bpermute lookup, LDS reduce, direct store ---
__global__ __launch_bounds__(256) void k_main(const unsigned short* __restrict__ G,
                                              const unsigned short* __restrict__ Vbf,
                                              const float* __restrict__ attn,
                                              const float* __restrict__ diff,
                                              const float* __restrict__ start,
                                              float* __restrict__ weighted) {
    const int b    = blockIdx.x / NVT;
    const int vt   = blockIdx.x % NVT;
    const int v0   = vt * 64;
    const int lane = threadIdx.x & 63;
    const int wv   = threadIdx.x >> 6;     // wave owns d range [wv*256, wv*256+256)
    const int lr   = lane & 15;
    const int grp  = lane >> 4;
    const int base4 = (lane & 48) << 2;    // bpermute byte-addr base

    // bin_w[lr] in-register: relu + inclusive prefix scan over the 16-lane group
    float dw = diff[lr]; dw = dw > 0.f ? dw : 0.f;
#pragma unroll
    for (int off = 1; off < 16; off <<= 1) {
        float t = __shfl_up(dw, off, 16);
        if (lr >= off) dw += t;
    }
    const float wl = start[0] + dw;        // lane holds bin_w[lane&15]

    // B fragments resident in VGPRs
    s16x8 bfr[4][4];
#pragma unroll
    for (int ct = 0; ct < 4; ++ct)
#pragma unroll
        for (int kc = 0; kc < 4; ++kc)
            bfr[ct][kc] = *reinterpret_cast<const s16x8*>(
                &Vbf[(size_t)(v0 + ct * 16 + lr) * KP + grp * 8 + kc * 32]);

    const float invD = 14.0f / 1.49f;
    const float C0   = 0.5f * invD + 1.0f;

    float acc[4] = {0.f, 0.f, 0.f, 0.f};
    const float* attb = attn + b * ND + wv * 256 + grp * 4;
    const unsigned short* __restrict__ Gp =
        G + ((size_t)(b * ND + wv * 256 + lr)) * KP + grp * 8;

    auto STEP = [&](const s16x8 af[4], int it) {
        float4 a4 = *reinterpret_cast<const float4*>(attb + it * 16);
        float at[4] = {a4.x, a4.y, a4.z, a4.w};
        float cc[16];
#pragma unroll
        for (int ct = 0; ct < 4; ++ct) {
            f32x4 c = {0.f, 0.f, 0.f, 0.f};
#pragma unroll
            for (int kc = 0; kc < 4; ++kc)
                c = __builtin_amdgcn_mfma_f32_16x16x32_bf16(af[kc], bfr[ct][kc], c, 0, 0, 0);
#pragma unroll
            for (int r = 0; r < 4; ++r) cc[ct * 4 + r] = c[r];
        }
        int ad[16];
#pragma unroll
        for (int e = 0; e < 16; ++e) {
            float x  = fmaf(cc[e], invD, C0);
            float xc = fminf(fmaxf(x, 0.f), 15.f);   // med3 clamp; trunc==floor for >=0
            ad[e] = (((int)xc) << 2) | base4;
        }
        float wv_[16];
#pragma unroll
        for (int e = 0; e < 16; ++e)
            wv_[e] = __int_as_float(__builtin_amdgcn_ds_bpermute(ad[e], __float_as_int(wl)));
#pragma unroll
        for (int e = 0; e < 16; ++e)
            acc[e >> 2] = fmaf(at[e & 3], wv_[e], acc[e >> 2]);
    };

    // double-buffered A-fragment loads over 16 iterations
    s16x8 afA[4], afB[4];
#pragma unroll
    for (int kc = 0; kc < 4; ++kc)
        afA[kc] = *reinterpret_cast<const s16x8*>(Gp + kc * 32);

    for (int it = 0; it < 16; it += 2) {
        const unsigned short* GpB = Gp + (size_t)(it + 1) * 16 * KP;
#pragma unroll
        for (int kc = 0; kc < 4; ++kc)
            afB[kc] = *reinterpret_cast<const s16x8*>(GpB + kc * 32);
        STEP(afA, it);
        int itn = (it + 2 < 16) ? it + 2 : it;       // clamp last prefetch (harmless reload)
        const unsigned short* GpA = Gp + (size_t)itn * 16 * KP;
#pragma unroll
        for (int kc = 0; kc < 4; ++kc)
            afA[kc] = *reinterpret_cast<const s16x8*>(GpA + kc * 32);
        STEP(afB, it + 1);
    }

    // cross-wave reduce in LDS, one coalesced store (block exclusively owns these 64 cols)
    __shared__ float red[4][64];
#pragma unroll
    for (int ct = 0; ct < 4; ++ct) {
        float a = acc[ct];
        a += __shfl_xor(a, 16, 64);
        a += __shfl_xor(a, 32, 64);
        if (lane < 16) red[wv][ct * 16 + lane] = a;
    }
    __syncthreads();
    if (threadIdx.x < 64) {
        float s = red[0][threadIdx.x] + red[1][threadIdx.x] +
                  red[2][threadIdx.x] + red[3][threadIdx.x];
        weighted[b * NVP + v0 + threadIdx.x] = s;
    }
}

// --- final: out[b,n] = <weighted[b,:], phi[n,:]> / max(L1(phi[n,:]),1e-12) ; 2 rows/block ---
__global__ __launch_bounds__(512) void k_final(const float* __restrict__ phi,
                                               const float* __restrict__ weighted,
                                               float* __restrict__ out) {
    const int n0 = blockIdx.x * 2;
    const int t = threadIdx.x;       // 512 threads = 8 waves
    float s1[2] = {0.f, 0.f};
    float dot[2][8];
#pragma unroll
    for (int nn = 0; nn < 2; ++nn)
#pragma unroll
        for (int b = 0; b < 8; ++b) dot[nn][b] = 0.f;

    for (int v4 = t; v4 < NV / 4; v4 += 512) {
        float4 w4[8];
#pragma unroll
        for (int b = 0; b < 8; ++b)
            w4[b] = *reinterpret_cast<const float4*>(&weighted[b * NVP + v4 * 4]);
#pragma unroll
        for (int nn = 0; nn < 2; ++nn) {
            float4 p = *reinterpret_cast<const float4*>(&phi[(size_t)(n0 + nn) * NV + v4 * 4]);
            s1[nn] += fabsf(p.x) + fabsf(p.y) + fabsf(p.z) + fabsf(p.w);
#pragma unroll
            for (int b = 0; b < 8; ++b)
                dot[nn][b] += p.x * w4[b].x + p.y * w4[b].y + p.z * w4[b].z + p.w * w4[b].w;
        }
    }

    float vals[18];
#pragma unroll
    for (int nn = 0; nn < 2; ++nn) vals[nn] = s1[nn];
#pragma unroll
    for (int nn = 0; nn < 2; ++nn)
#pragma unroll
        for (int b = 0; b < 8; ++b) vals[2 + nn * 8 + b] = dot[nn][b];

    __shared__ float red[8][18];
    __shared__ float sums[18];
    const int lane = t & 63, wvv = t >> 6;
#pragma unroll
    for (int i = 0; i < 18; ++i) {
        float x = vals[i];
        x += __shfl_down(x, 32, 64);
        x += __shfl_down(x, 16, 64);
        x += __shfl_down(x, 8, 64);
        x += __shfl_down(x, 4, 64);
        x += __shfl_down(x, 2, 64);
        x += __shfl_down(x, 1, 64);
        if (lane == 0) red[wvv][i] = x;
    }
    __syncthreads();
    if (t < 18) {
        float s = 0.f;
        for (int w = 0; w < 8; ++w) s += red[w][t];
        sums[t] = s;
    }
    __syncthreads();
    if (t < 16) {
        int nn = t >> 3, b = t & 7;
        float denom = sums[nn]; if (denom < 1e-12f) denom = 1e-12f;
        out[b * NC + n0 + nn] = sums[2 + t] / denom;
    }
}

extern "C" void kernel_launch(void* const* d_in, const int* in_sizes, int n_in,
                              void* d_out, int out_size, void* d_ws, size_t ws_size,
                              hipStream_t stream) {
    const int*   doc   = (const int*)d_in[0];
    const float* attn  = (const float*)d_in[1];
    const float* emb   = (const float*)d_in[2];
    const float* VvT   = (const float*)d_in[3];
    const float* phi   = (const float*)d_in[4];
    const float* diff  = (const float*)d_in[5];
    const float* start = (const float*)d_in[6];

    char* ws = (char*)d_ws;
    unsigned short* Vbf = (unsigned short*)ws;                 // 30016*128*2 = 7,684,096 B
    unsigned short* G   = (unsigned short*)(ws + 7684096);     // 8192*128*2  = 2,097,152 B
    float* weighted     = (float*)(ws + 7684096 + 2097152);    // 8*30016*4   =   960,512 B
    float* out          = (float*)d_out;

    k_prep  <<<4565, 256, 0, stream>>>(doc, emb, VvT, G, Vbf);
    k_main  <<<B_ * NVT, 256, 0, stream>>>(G, Vbf, attn, diff, start, weighted);
    k_final <<<NC / 2, 512, 0, stream>>>(phi, weighted, out);
}